// Round 16
// baseline (481.406 us; speedup 1.0000x reference)
//
#include <hip/hip_runtime.h>
#include <hip/hip_bf16.h>

typedef __hip_bfloat16 bf16;
__device__ __forceinline__ float b2f(bf16 v){ return __bfloat162float(v); }

typedef __attribute__((ext_vector_type(8))) short s8v;
typedef __attribute__((ext_vector_type(4))) float f4v;

#define N_NODES 16384
#define N_EDGES 65536
#define NB 256
#define LSEQ 1000
#define BN_EPS 1e-5f
#define W1O 985
#define W2O 970
#define W3O 955
#define C1S 988          // g_c1o row stride (floats), layout [b][32 ch][C1S]
#define C2S 976          // g_c2o row stride (floats), layout [b][32 ch][C2S]

// ---- dtype flag: 1 if float inputs are f32, 0 if bf16 (measured: f32 on this harness) ----
__device__ int g_isf32;

__device__ __forceinline__ float LD(const void* p, int i, int f){
    return f ? ((const float*)p)[i] : b2f(((const bf16*)p)[i]);
}

// f32 -> bf16 bits, round-to-nearest-even
__device__ __forceinline__ unsigned short f2b(float x){
    unsigned u = __float_as_uint(x);
    return (unsigned short)((u + 0x7FFFu + ((u >> 16) & 1u)) >> 16);
}
__device__ __forceinline__ float bb2f(unsigned short h){
    return __uint_as_float(((unsigned)h) << 16);
}

__global__ void k_dtype(const void* x){
    if (threadIdx.x != 0 || blockIdx.x != 0) return;
    const unsigned short* u = (const unsigned short*)x;
    int insane = 0;
    for (int i = 0; i < 512; i++){
        unsigned short h = u[i];
        int ex = (h >> 7) & 0xFF;
        if (!(h == 0 || (ex >= 96 && ex <= 142))) insane++;
    }
    g_isf32 = (insane > 50) ? 1 : 0;
}

// ---- intermediates in device globals ----
__device__ float g_hA[N_NODES*32];
__device__ float g_hB[N_NODES*32];
__device__ float g_xd[NB*128];
__device__ float g_P[16*26*32];
__device__ float g_wsum[32*128];
__device__ float g_xdb[NB*32];
__device__ float g_xcm[NB*32];
__device__ float g_c1o[NB*32*C1S];   // 32.4 MB, [b][o][w]
__device__ float g_c2o[NB*32*C2S];   // 32.0 MB, [b][o][w]
// pre-packed conv weights in per-lane B-FRAGMENT order (s8v granularity):
// s8v index = ktg*256 + ogrp*128 + hl*64 + lane
__device__ __attribute__((aligned(16))) unsigned short g_wf[2][32768];
// CSR of the (fixed) edge list, destination-major
__device__ int g_deg[N_NODES];
__device__ int g_cur[N_NODES];
__device__ int g_rowptr[N_NODES + 1];
__device__ int g_csrc[N_EDGES];
__device__ int g_gstart[NB + 1];     // per-graph node ranges (batch is sorted)

// merged zeroing: deg (16384 ints) + xcm (8192 floats); grid 96
__global__ void k_zero(){
    int i = blockIdx.x*256 + threadIdx.x;
    if (i < N_NODES) g_deg[i] = 0;
    else g_xcm[i - N_NODES] = 0.f;
}

// ---- CSR build (once per launch) ----
__global__ void k_count(const int* __restrict__ ei){
    int e = blockIdx.x*256 + threadIdx.x;                                    // grid 256
    atomicAdd(&g_deg[ei[N_EDGES + e]], 1);
}
__global__ __launch_bounds__(1024) void k_scan(){                            // 1 block
    __shared__ int part[1024];
    int t = threadIdx.x;
    int base = t*16;
    int s = 0;
    #pragma unroll
    for (int i = 0; i < 16; i++) s += g_deg[base + i];
    part[t] = s;
    __syncthreads();
    for (int off = 1; off < 1024; off <<= 1){
        int v = (t >= off) ? part[t - off] : 0;
        __syncthreads();
        part[t] += v;
        __syncthreads();
    }
    int run = (t == 0) ? 0 : part[t - 1];
    for (int i = 0; i < 16; i++){
        g_rowptr[base + i] = run;
        g_cur[base + i] = run;
        run += g_deg[base + i];
    }
    if (t == 1023) g_rowptr[N_NODES] = run;
}
__global__ void k_fill(const int* __restrict__ ei){
    int e = blockIdx.x*256 + threadIdx.x;                                    // grid 256
    int d = ei[N_EDGES + e];
    int slot = atomicAdd(&g_cur[d], 1);
    g_csrc[slot] = ei[e];
}
__global__ void k_ranges(const int* __restrict__ batch){                     // 1 block, 256 thr
    int b = threadIdx.x;
    int lo = 0, hi = N_NODES;
    while (lo < hi){ int mid = (lo + hi) >> 1; if (batch[mid] < b) lo = mid + 1; else hi = mid; }
    g_gstart[b] = lo;
    if (b == 0) g_gstart[NB] = N_NODES;
}

// ---- weight pre-pack into fragment order ----
__global__ void k_wpack(const void* w2, const void* w3){
    const int F = g_isf32;
    int idx = blockIdx.x*256 + threadIdx.x;      // 65536 threads
    int sel = idx >> 15;
    int r = idx & 32767;
    int j = r & 7;
    int lane = (r >> 3) & 63;
    int hl = (r >> 9) & 1;
    int ogrp = (r >> 10) & 1;
    int ktg = r >> 11;
    int c = (lane >> 4)*8 + j;
    int o = ogrp*16 + (lane & 15);
    const void* Wt = sel ? w3 : w2;
    float wv = LD(Wt, o*512 + c*16 + ktg, F);
    unsigned short h = f2b(wv);
    g_wf[sel][r] = hl ? f2b(wv - bb2f(h)) : h;
}

// ---------------- GIN branch (CSR gather fused; 8 nodes per block) ----------

__global__ __launch_bounds__(256) void k_proj78(const void* x, const void* W1)
{
    const int F = g_isf32;
    __shared__ float sW1[78*32];
    __shared__ float sx[8][78];
    int tid = threadIdx.x;
    for (int i = tid; i < 78*32; i += 256) sW1[i] = LD(W1, i, F);
    int nodeBase = blockIdx.x * 8;
    for (int i = tid; i < 8*78; i += 256){
        int ln = i / 78, f = i - ln*78;
        sx[ln][f] = LD(x, (nodeBase + ln)*78 + f, F);
    }
    __syncthreads();
    int ln = tid >> 5, j = tid & 31;
    float a = 0.f;
    #pragma unroll 6
    for (int i = 0; i < 78; i++) a += sx[ln][i] * sW1[i*32 + j];
    g_hA[(nodeBase + ln)*32 + j] = a;
}

// cooperative edge gather: 32 lanes of a node load up to 32 indices at once,
// broadcast via shuffle -> feature gathers become independent (same sum order)
__device__ __forceinline__ float csr_gather(const float* hin, int n, int j){
    int rs = g_rowptr[n];
    int deg = g_rowptr[n + 1] - rs;
    float agg = 0.f;
    for (int base = 0; base < deg; base += 32){
        int cnt = deg - base; if (cnt > 32) cnt = 32;
        int myidx = (j < cnt) ? g_csrc[rs + base + j] : 0;
        for (int e = 0; e < cnt; e++){
            int src = __shfl(myidx, e, 32);
            agg += hin[src*32 + j];
        }
    }
    return agg;
}

// hA -> hB
__global__ __launch_bounds__(256) void k_gin1b(
    const void* b1, const void* W2, const void* b2,
    const void* bng, const void* bnb, const void* bnm, const void* bnv)
{
    const int F = g_isf32;
    __shared__ float sW2[32*32];
    __shared__ float sb1[32], sb2[32], sA[32], sB[32];
    __shared__ float st[8][32];
    int tid = threadIdx.x;
    for (int i = tid; i < 1024; i += 256) sW2[i] = LD(W2, i, F);
    if (tid < 32){
        sb1[tid] = LD(b1, tid, F); sb2[tid] = LD(b2, tid, F);
        float inv = LD(bng, tid, F) * rsqrtf(LD(bnv, tid, F) + BN_EPS);
        sA[tid] = inv;
        sB[tid] = LD(bnb, tid, F) - LD(bnm, tid, F) * inv;
    }
    __syncthreads();
    int ln = tid >> 5, j = tid & 31;
    int n = blockIdx.x*8 + ln;
    float agg = csr_gather(g_hA, n, j);
    st[ln][j] = fmaxf(g_hA[n*32 + j] + agg + sb1[j], 0.f);
    __syncthreads();
    float t2 = sb2[j];
    #pragma unroll
    for (int i = 0; i < 32; i++) t2 += st[ln][i] * sW2[i*32 + j];
    t2 = fmaxf(t2, 0.f);
    g_hB[n*32 + j] = t2 * sA[j] + sB[j];
}

// alternating hB->hA (l even) / hA->hB (l odd)
__global__ __launch_bounds__(256) void k_gin32L(
    const void* W1, const void* b1, const void* W2, const void* b2,
    const void* bng, const void* bnb, const void* bnm, const void* bnv, int l)
{
    const int F = g_isf32;
    const float* hin = (l & 1) ? g_hA : g_hB;
    float* hout = (l & 1) ? g_hB : g_hA;
    const int oW = l*1024, ob = l*32, obn = (l+1)*32;
    __shared__ float sW1[32*32], sW2[32*32];
    __shared__ float sb1[32], sb2[32], sA[32], sB[32];
    __shared__ float sh[8][32], st[8][32];
    int tid = threadIdx.x;
    for (int i = tid; i < 1024; i += 256){ sW1[i] = LD(W1, oW + i, F); sW2[i] = LD(W2, oW + i, F); }
    if (tid < 32){
        sb1[tid] = LD(b1, ob + tid, F); sb2[tid] = LD(b2, ob + tid, F);
        float inv = LD(bng, obn + tid, F) * rsqrtf(LD(bnv, obn + tid, F) + BN_EPS);
        sA[tid] = inv;
        sB[tid] = LD(bnb, obn + tid, F) - LD(bnm, obn + tid, F) * inv;
    }
    int ln = tid >> 5, j = tid & 31;
    int n = blockIdx.x*8 + ln;
    float agg = csr_gather(hin, n, j);
    sh[ln][j] = hin[n*32 + j] + agg;
    __syncthreads();
    float t1 = sb1[j];
    #pragma unroll
    for (int i = 0; i < 32; i++) t1 += sh[ln][i] * sW1[i*32 + j];
    st[ln][j] = fmaxf(t1, 0.f);
    __syncthreads();
    float t2 = sb2[j];
    #pragma unroll
    for (int i = 0; i < 32; i++) t2 += st[ln][i] * sW2[i*32 + j];
    t2 = fmaxf(t2, 0.f);
    hout[n*32 + j] = t2 * sA[j] + sB[j];
}

// fused pool (range-based, batch sorted) + xd; final h lives in g_hB
__global__ __launch_bounds__(256) void k_poolxd(const void* W, const void* bias){
    const int F = g_isf32;
    __shared__ float red[8][32];
    int b = blockIdx.x, tid = threadIdx.x;
    int j = tid & 31, sub = tid >> 5;
    int s = g_gstart[b], e = g_gstart[b + 1];
    float a = 0.f;
    for (int n = s + sub; n < e; n += 8) a += g_hB[n*32 + j];
    red[sub][j] = a;
    __syncthreads();
    if (sub == 0){
        red[0][j] = red[0][j] + red[1][j] + red[2][j] + red[3][j]
                  + red[4][j] + red[5][j] + red[6][j] + red[7][j];
    }
    __syncthreads();
    if (tid < 128){
        float acc = LD(bias, tid, F);
        #pragma unroll
        for (int i = 0; i < 32; i++) acc += red[0][i] * LD(W, i*128 + tid, F);
        g_xd[b*128 + tid] = fmaxf(acc, 0.f);
    }
}

// ---------------- conv1 prep (P table + wsum merged; xdbias separate) --------

__global__ void k_Pw(const void* embed, const void* c1W){
    const int F = g_isf32;
    if (blockIdx.x < 52){
        int idx = blockIdx.x*256 + threadIdx.x;
        if (idx >= 16*26*32) return;
        int o = idx & 31;
        int t = (idx >> 5) % 26;
        int k = idx / (32*26);
        float a = 0.f;
        for (int c = 0; c < 128; c++)
            a += LD(embed, t*128 + c, F) * LD(c1W, o*4096 + c*16 + k, F);
        g_P[(k*26 + t)*32 + o] = a;
    } else {
        int idx = (blockIdx.x - 52)*256 + threadIdx.x;   // 4096 threads
        int o = idx >> 7, c = idx & 127;
        float a = 0.f;
        #pragma unroll
        for (int k = 0; k < 16; k++) a += LD(c1W, o*4096 + (128 + c)*16 + k, F);
        g_wsum[o*128 + c] = a;
    }
}

__global__ void k_xdbias(const void* c1b){
    const int F = g_isf32;
    int idx = blockIdx.x*256 + threadIdx.x;
    int b = idx >> 5, o = idx & 31;
    float a = LD(c1b, o, F);
    for (int c = 0; c < 128; c++) a += g_xd[b*128 + c] * g_wsum[o*128 + c];
    g_xdb[idx] = a;
}

// writes [b][o][w] (stride C1S); grid NB*4, each block does a w-quarter
__global__ __launch_bounds__(256) void k_conv1L(
    const int* __restrict__ target,
    const void* g, const void* be, const void* m, const void* v, int obn)
{
    const int F = g_isf32;
    __shared__ float sP[16*26*32];
    __shared__ int   stg[LSEQ];
    __shared__ float sxb[32], sA[32], sB[32];
    int b = blockIdx.x >> 2, q = blockIdx.x & 3;
    int tid = threadIdx.x;
    for (int i = tid; i < 16*26*32; i += 256) sP[i] = g_P[i];
    for (int i = tid; i < LSEQ; i += 256) stg[i] = target[b*LSEQ + i];
    if (tid < 32){
        sxb[tid] = g_xdb[b*32 + tid];
        float inv = LD(g, obn + tid, F) * rsqrtf(LD(v, obn + tid, F) + BN_EPS);
        sA[tid] = inv;
        sB[tid] = LD(be, obn + tid, F) - LD(m, obn + tid, F) * inv;
    }
    __syncthreads();
    int o = tid & 31, wsub = tid >> 5;
    float xb = sxb[o], aa = sA[o], bb = sB[o];
    int wlo = q*248;
    int whi = (q == 3) ? W1O : wlo + 248;
    for (int w = wlo + wsub; w < whi; w += 8){
        float a = xb;
        #pragma unroll
        for (int k = 0; k < 16; k++)
            a += sP[(k*26 + stg[w + k])*32 + o];
        g_c1o[(b*32 + o)*C1S + w] = fmaxf(a * aa + bb, 0.f);
    }
}

// ---------------- conv2/conv3 via MFMA, double-bf16 split (r13, FROZEN) ------

#define CT_W 128
#define CT_R 144     // 128 + 15 halo, padded
#define CPAD 40      // c-row pad: 80 B = 16B-aligned rows

__global__ __launch_bounds__(256) void k_cmfma(
    int sel, int Wvalid, int Wout, int inStride,
    const void* bias, const void* g, const void* be,
    const void* m, const void* v, int obn)
{
    const int F = g_isf32;
    const float* in = (sel == 0) ? g_c1o : g_c2o;
    __shared__ __attribute__((aligned(16))) unsigned short sAh[CT_R*CPAD]; // 11520 B
    __shared__ __attribute__((aligned(16))) unsigned short sAl[CT_R*CPAD]; // 11520 B
    __shared__ float sSc[32], sOf[32];
    int tid = threadIdx.x;
    int b = blockIdx.x >> 3;
    int tile = blockIdx.x & 7;
    int wbase = tile * CT_W;

    for (int c = 0; c < 32; c++){
        const float* src = in + (b*32 + c)*inStride;
        if (tid < CT_R){
            int wg_ = wbase + tid;
            float xv = (wg_ < Wvalid) ? src[wg_] : 0.f;
            unsigned short h = f2b(xv);
            sAh[tid*CPAD + c] = h;
            sAl[tid*CPAD + c] = f2b(xv - bb2f(h));
        }
    }
    if (tid < 32){
        float inv = LD(g, obn + tid, F) * rsqrtf(LD(v, obn + tid, F) + BN_EPS);
        sSc[tid] = inv;
        sOf[tid] = LD(be, obn + tid, F) + (LD(bias, tid, F) - LD(m, obn + tid, F)) * inv;
    }
    __syncthreads();                 // the ONLY barrier

    int lane = tid & 63;
    int wv = tid >> 6;
    int ml = lane & 15, quad = lane >> 4;
    int wgrp = wv & 1;
    int ogrp = wv >> 1;

    const s8v* wfb = (const s8v*)&g_wf[sel][0] + ogrp*128 + lane;

    f4v acc[4];
    #pragma unroll
    for (int mt = 0; mt < 4; mt++) acc[mt] = (f4v){0.f, 0.f, 0.f, 0.f};

    s8v nbh = wfb[0], nbl = wfb[64];
    for (int ktg = 0; ktg < 16; ktg++){
        s8v bh = nbh, bl = nbl;
        if (ktg < 15){
            nbh = wfb[(ktg + 1)*256];
            nbl = wfb[(ktg + 1)*256 + 64];
        }
        #pragma unroll
        for (int mt = 0; mt < 4; mt++){
            int row = wgrp*64 + mt*16 + ml + ktg;
            const int aidx = row*CPAD + quad*8;
            s8v ah = *(const s8v*)&sAh[aidx];
            s8v al = *(const s8v*)&sAl[aidx];
            acc[mt] = __builtin_amdgcn_mfma_f32_16x16x32_bf16(ah, bh, acc[mt], 0, 0, 0);
            acc[mt] = __builtin_amdgcn_mfma_f32_16x16x32_bf16(ah, bl, acc[mt], 0, 0, 0);
            acc[mt] = __builtin_amdgcn_mfma_f32_16x16x32_bf16(al, bh, acc[mt], 0, 0, 0);
        }
    }

    int o = ogrp*16 + ml;
    float sc = sSc[o], of = sOf[o];
    #pragma unroll
    for (int mt = 0; mt < 4; mt++){
        int w0 = wbase + wgrp*64 + mt*16 + quad*4;
        f4v a = acc[mt];
        float y0 = fmaxf(a.x*sc + of, 0.f);
        float y1 = fmaxf(a.y*sc + of, 0.f);
        float y2 = fmaxf(a.z*sc + of, 0.f);
        float y3 = fmaxf(a.w*sc + of, 0.f);
        if (sel == 0){
            float* dst = &g_c2o[(b*32 + o)*C2S + w0];
            if (w0 + 3 < Wout){
                *(float4*)dst = make_float4(y0, y1, y2, y3);
            } else if (w0 < Wout){
                dst[0] = y0;
                if (w0+1 < Wout) dst[1] = y1;
                if (w0+2 < Wout) dst[2] = y2;
                if (w0+3 < Wout) dst[3] = y3;
            }
        } else {
            if (w0 < Wout){
                float mx = y0;
                if (w0+1 < Wout) mx = fmaxf(mx, y1);
                if (w0+2 < Wout) mx = fmaxf(mx, y2);
                if (w0+3 < Wout) mx = fmaxf(mx, y3);
                atomicMax((int*)&g_xcm[b*32 + o], __float_as_int(mx));
            }
        }
    }
}

// ---------------- fused FC tail: xcf -> fc1 -> fc2 -> out (per-b) -----------

__global__ __launch_bounds__(1024) void k_tail(
    const void* fcxcW, const void* fcxcb,
    const void* bg, const void* bb, const void* bm, const void* bv,
    const void* fc1W, const void* fc1b,
    const void* fc2W, const void* fc2b,
    const void* outW, const void* outb, void* out)
{
    const int F = g_isf32;
    __shared__ float sz[256];
    __shared__ float z1s[1024];
    __shared__ float sp[4][256];
    int b = blockIdx.x, t = threadIdx.x;
    if (t < 128) sz[t] = g_xd[b*128 + t];
    else if (t < 256){
        int j = t - 128;
        float a = LD(fcxcb, j, F);
        #pragma unroll
        for (int i = 0; i < 32; i++) a += g_xcm[b*32 + i] * LD(fcxcW, i*128 + j, F);
        float inv = LD(bg, j, F) * rsqrtf(LD(bv, j, F) + BN_EPS);
        a = (a - LD(bm, j, F)) * inv + LD(bb, j, F);
        sz[t] = fmaxf(a, 0.f);
    }
    __syncthreads();
    // fc1: 1024 outputs, one per thread
    float a = LD(fc1b, t, F);
    for (int i = 0; i < 256; i++) a += sz[i] * LD(fc1W, i*1024 + t, F);
    z1s[t] = fmaxf(a, 0.f);
    __syncthreads();
    // fc2: 256 outputs, 4-way K-split
    int j = t & 255, kq = t >> 8;
    float a2 = 0.f;
    #pragma unroll 8
    for (int i = 0; i < 256; i++)
        a2 += z1s[kq*256 + i] * LD(fc2W, (kq*256 + i)*256 + j, F);
    sp[kq][j] = a2;
    __syncthreads();
    if (t < 256){
        float z2 = fmaxf(sp[0][t] + sp[1][t] + sp[2][t] + sp[3][t] + LD(fc2b, t, F), 0.f);
        sp[0][t] = z2 * LD(outW, t, F);
    }
    __syncthreads();
    for (int s = 128; s > 0; s >>= 1){
        if (t < s) sp[0][t] += sp[0][t + s];
        __syncthreads();
    }
    if (t == 0){
        float r = sp[0][0] + LD(outb, 0, F);
        if (F) ((float*)out)[b] = r;
        else   ((bf16*)out)[b] = __float2bfloat16(r);
    }
}

// ---------------- launch ----------------

extern "C" void kernel_launch(void* const* d_in, const int* in_sizes, int n_in,
                              void* d_out, int out_size, void* d_ws, size_t ws_size,
                              hipStream_t stream)
{
    (void)in_sizes; (void)n_in; (void)out_size; (void)d_ws; (void)ws_size;
    const void* x      = d_in[0];
    const int*  ei     = (const int*)d_in[1];
    const int*  batch  = (const int*)d_in[2];
    const int*  target = (const int*)d_in[3];
    const void* g1W1 = d_in[4];  const void* g1b1 = d_in[5];
    const void* g1W2 = d_in[6];  const void* g1b2 = d_in[7];
    const void* gW1  = d_in[8];  const void* gb1  = d_in[9];
    const void* gW2  = d_in[10]; const void* gb2  = d_in[11];
    const void* bng  = d_in[12]; const void* bnb  = d_in[13];
    const void* bnm  = d_in[14]; const void* bnv  = d_in[15];
    const void* fcxdW = d_in[16]; const void* fcxdb = d_in[17];
    const void* embed = d_in[18];
    const void* c1W = d_in[19]; const void* c1b = d_in[20];
    const void* c2W = d_in[21]; const void* c2b = d_in[22];
    const void* c3W = d_in[23]; const void* c3b = d_in[24];
    const void* cbng = d_in[25]; const void* cbnb = d_in[26];
    const void* cbnm = d_in[27]; const void* cbnv = d_in[28];
    const void* fcxcW = d_in[29]; const void* fcxcb = d_in[30];
    const void* bnfcg = d_in[31]; const void* bnfcb = d_in[32];
    const void* bnfcm = d_in[33]; const void* bnfcv = d_in[34];
    const void* fc1W = d_in[35]; const void* fc1b = d_in[36];
    const void* fc2W = d_in[37]; const void* fc2b = d_in[38];
    const void* outW = d_in[39]; const void* outb = d_in[40];

    k_dtype<<<1, 64, 0, stream>>>(x);
    k_wpack<<<256, 256, 0, stream>>>(c2W, c3W);

    // ---- CSR build ----
    k_zero<<<(N_NODES + NB*32)/256, 256, 0, stream>>>();
    k_count<<<N_EDGES/256, 256, 0, stream>>>(ei);
    k_scan<<<1, 1024, 0, stream>>>();
    k_fill<<<N_EDGES/256, 256, 0, stream>>>(ei);
    k_ranges<<<1, 256, 0, stream>>>(batch);

    // ---- GIN chain (8 nodes/block; h ping-pongs hA->hB->hA->...) ----
    k_proj78<<<N_NODES/8, 256, 0, stream>>>(x, g1W1);
    k_gin1b<<<N_NODES/8, 256, 0, stream>>>(g1b1, g1W2, g1b2, bng, bnb, bnm, bnv);
    for (int l = 0; l < 4; l++){
        k_gin32L<<<N_NODES/8, 256, 0, stream>>>(gW1, gb1, gW2, gb2,
                                                bng, bnb, bnm, bnv, l);
    }
    // ---- pool+xd fused ----
    k_poolxd<<<NB, 256, 0, stream>>>(fcxdW, fcxdb);
    // ---- conv1 prep ----
    k_Pw<<<68, 256, 0, stream>>>(embed, c1W);
    k_xdbias<<<32, 256, 0, stream>>>(c1b);
    // ---- conv chain ----
    k_conv1L<<<NB*4, 256, 0, stream>>>(target, cbng, cbnb, cbnm, cbnv, 0);
    k_cmfma<<<NB*8, 256, 0, stream>>>(0, W1O, W2O, C1S,
                                      c2b, cbng, cbnb, cbnm, cbnv, 32);
    k_cmfma<<<NB*8, 256, 0, stream>>>(1, W2O, W3O, C2S,
                                      c3b, cbng, cbnb, cbnm, cbnv, 64);
    // ---- fused FC tail ----
    k_tail<<<NB, 1024, 0, stream>>>(fcxcW, fcxcb, bnfcg, bnfcb, bnfcm, bnfcv,
                                    fc1W, fc1b, fc2W, fc2b, outW, outb, d_out);
}

// Round 17
// 477.522 us; speedup vs baseline: 1.0081x; 1.0081x over previous
//
#include <hip/hip_runtime.h>
#include <hip/hip_bf16.h>

typedef __hip_bfloat16 bf16;
__device__ __forceinline__ float b2f(bf16 v){ return __bfloat162float(v); }

typedef __attribute__((ext_vector_type(8))) short s8v;
typedef __attribute__((ext_vector_type(4))) float f4v;

#define N_NODES 16384
#define N_EDGES 65536
#define NB 256
#define LSEQ 1000
#define BN_EPS 1e-5f
#define W1O 985
#define W2O 970
#define W3O 955
#define C1S 988          // g_c1o row stride (floats), layout [b][32 ch][C1S]
#define C2S 976          // g_c2o row stride (floats), layout [b][32 ch][C2S]

// ---- dtype flag: 1 if float inputs are f32, 0 if bf16 (measured: f32 on this harness) ----
__device__ int g_isf32;

__device__ __forceinline__ float LD(const void* p, int i, int f){
    return f ? ((const float*)p)[i] : b2f(((const bf16*)p)[i]);
}

// f32 -> bf16 bits, round-to-nearest-even
__device__ __forceinline__ unsigned short f2b(float x){
    unsigned u = __float_as_uint(x);
    return (unsigned short)((u + 0x7FFFu + ((u >> 16) & 1u)) >> 16);
}
__device__ __forceinline__ float bb2f(unsigned short h){
    return __uint_as_float(((unsigned)h) << 16);
}

__global__ void k_dtype(const void* x){
    if (threadIdx.x != 0 || blockIdx.x != 0) return;
    const unsigned short* u = (const unsigned short*)x;
    int insane = 0;
    for (int i = 0; i < 512; i++){
        unsigned short h = u[i];
        int ex = (h >> 7) & 0xFF;
        if (!(h == 0 || (ex >= 96 && ex <= 142))) insane++;
    }
    g_isf32 = (insane > 50) ? 1 : 0;
}

// ---- intermediates in device globals ----
__device__ float g_hA[N_NODES*32];
__device__ float g_hB[N_NODES*32];
__device__ float g_xd[NB*128];
__device__ float g_P[16*26*32];
__device__ float g_wsum[32*128];
__device__ float g_xdb[NB*32];
__device__ float g_xcm[NB*32];
__device__ float g_c1o[NB*32*C1S];   // 32.4 MB, [b][o][w]
__device__ float g_c2o[NB*32*C2S];   // 32.0 MB, [b][o][w]
// pre-packed conv weights in per-lane B-FRAGMENT order (s8v granularity):
// s8v index = ktg*256 + ogrp*128 + hl*64 + lane
__device__ __attribute__((aligned(16))) unsigned short g_wf[2][32768];
// CSR of the (fixed) edge list, destination-major
__device__ int g_deg[N_NODES];
__device__ int g_cur[N_NODES];
__device__ int g_rowptr[N_NODES + 1];
__device__ int g_csrc[N_EDGES];
__device__ int g_gstart[NB + 1];     // per-graph node ranges (batch is sorted)

// merged zeroing: deg (16384 ints) + xcm (8192 floats); grid 96
__global__ void k_zero(){
    int i = blockIdx.x*256 + threadIdx.x;
    if (i < N_NODES) g_deg[i] = 0;
    else g_xcm[i - N_NODES] = 0.f;
}

// ---- CSR build (once per launch) ----
__global__ void k_count(const int* __restrict__ ei){
    int e = blockIdx.x*256 + threadIdx.x;                                    // grid 256
    atomicAdd(&g_deg[ei[N_EDGES + e]], 1);
}
__global__ __launch_bounds__(1024) void k_scan(){                            // 1 block
    __shared__ int part[1024];
    int t = threadIdx.x;
    int base = t*16;
    int s = 0;
    #pragma unroll
    for (int i = 0; i < 16; i++) s += g_deg[base + i];
    part[t] = s;
    __syncthreads();
    for (int off = 1; off < 1024; off <<= 1){
        int v = (t >= off) ? part[t - off] : 0;
        __syncthreads();
        part[t] += v;
        __syncthreads();
    }
    int run = (t == 0) ? 0 : part[t - 1];
    for (int i = 0; i < 16; i++){
        g_rowptr[base + i] = run;
        g_cur[base + i] = run;
        run += g_deg[base + i];
    }
    if (t == 1023) g_rowptr[N_NODES] = run;
}
__global__ void k_fill(const int* __restrict__ ei){
    int e = blockIdx.x*256 + threadIdx.x;                                    // grid 256
    int d = ei[N_EDGES + e];
    int slot = atomicAdd(&g_cur[d], 1);
    g_csrc[slot] = ei[e];
}
__global__ void k_ranges(const int* __restrict__ batch){                     // 1 block, 256 thr
    int b = threadIdx.x;
    int lo = 0, hi = N_NODES;
    while (lo < hi){ int mid = (lo + hi) >> 1; if (batch[mid] < b) lo = mid + 1; else hi = mid; }
    g_gstart[b] = lo;
    if (b == 0) g_gstart[NB] = N_NODES;
}

// ---- weight pre-pack into fragment order ----
__global__ void k_wpack(const void* w2, const void* w3){
    const int F = g_isf32;
    int idx = blockIdx.x*256 + threadIdx.x;      // 65536 threads
    int sel = idx >> 15;
    int r = idx & 32767;
    int j = r & 7;
    int lane = (r >> 3) & 63;
    int hl = (r >> 9) & 1;
    int ogrp = (r >> 10) & 1;
    int ktg = r >> 11;
    int c = (lane >> 4)*8 + j;
    int o = ogrp*16 + (lane & 15);
    const void* Wt = sel ? w3 : w2;
    float wv = LD(Wt, o*512 + c*16 + ktg, F);
    unsigned short h = f2b(wv);
    g_wf[sel][r] = hl ? f2b(wv - bb2f(h)) : h;
}

// ---------------- GIN branch (CSR gather fused; 8 nodes per block) ----------

__global__ __launch_bounds__(256) void k_proj78(const void* x, const void* W1)
{
    const int F = g_isf32;
    __shared__ float sW1[78*32];
    __shared__ float sx[8][78];
    int tid = threadIdx.x;
    for (int i = tid; i < 78*32; i += 256) sW1[i] = LD(W1, i, F);
    int nodeBase = blockIdx.x * 8;
    for (int i = tid; i < 8*78; i += 256){
        int ln = i / 78, f = i - ln*78;
        sx[ln][f] = LD(x, (nodeBase + ln)*78 + f, F);
    }
    __syncthreads();
    int ln = tid >> 5, j = tid & 31;
    float a = 0.f;
    #pragma unroll 6
    for (int i = 0; i < 78; i++) a += sx[ln][i] * sW1[i*32 + j];
    g_hA[(nodeBase + ln)*32 + j] = a;
}

// cooperative edge gather: 32 lanes of a node load up to 32 indices at once,
// broadcast via shuffle -> feature gathers become independent (same sum order)
__device__ __forceinline__ float csr_gather(const float* hin, int n, int j){
    int rs = g_rowptr[n];
    int deg = g_rowptr[n + 1] - rs;
    float agg = 0.f;
    for (int base = 0; base < deg; base += 32){
        int cnt = deg - base; if (cnt > 32) cnt = 32;
        int myidx = (j < cnt) ? g_csrc[rs + base + j] : 0;
        for (int e = 0; e < cnt; e++){
            int src = __shfl(myidx, e, 32);
            agg += hin[src*32 + j];
        }
    }
    return agg;
}

// hA -> hB
__global__ __launch_bounds__(256) void k_gin1b(
    const void* b1, const void* W2, const void* b2,
    const void* bng, const void* bnb, const void* bnm, const void* bnv)
{
    const int F = g_isf32;
    __shared__ float sW2[32*32];
    __shared__ float sb1[32], sb2[32], sA[32], sB[32];
    __shared__ float st[8][32];
    int tid = threadIdx.x;
    for (int i = tid; i < 1024; i += 256) sW2[i] = LD(W2, i, F);
    if (tid < 32){
        sb1[tid] = LD(b1, tid, F); sb2[tid] = LD(b2, tid, F);
        float inv = LD(bng, tid, F) * rsqrtf(LD(bnv, tid, F) + BN_EPS);
        sA[tid] = inv;
        sB[tid] = LD(bnb, tid, F) - LD(bnm, tid, F) * inv;
    }
    __syncthreads();
    int ln = tid >> 5, j = tid & 31;
    int n = blockIdx.x*8 + ln;
    float agg = csr_gather(g_hA, n, j);
    st[ln][j] = fmaxf(g_hA[n*32 + j] + agg + sb1[j], 0.f);
    __syncthreads();
    float t2 = sb2[j];
    #pragma unroll
    for (int i = 0; i < 32; i++) t2 += st[ln][i] * sW2[i*32 + j];
    t2 = fmaxf(t2, 0.f);
    g_hB[n*32 + j] = t2 * sA[j] + sB[j];
}

// alternating hB->hA (l even) / hA->hB (l odd)
__global__ __launch_bounds__(256) void k_gin32L(
    const void* W1, const void* b1, const void* W2, const void* b2,
    const void* bng, const void* bnb, const void* bnm, const void* bnv, int l)
{
    const int F = g_isf32;
    const float* hin = (l & 1) ? g_hA : g_hB;
    float* hout = (l & 1) ? g_hB : g_hA;
    const int oW = l*1024, ob = l*32, obn = (l+1)*32;
    __shared__ float sW1[32*32], sW2[32*32];
    __shared__ float sb1[32], sb2[32], sA[32], sB[32];
    __shared__ float sh[8][32], st[8][32];
    int tid = threadIdx.x;
    for (int i = tid; i < 1024; i += 256){ sW1[i] = LD(W1, oW + i, F); sW2[i] = LD(W2, oW + i, F); }
    if (tid < 32){
        sb1[tid] = LD(b1, ob + tid, F); sb2[tid] = LD(b2, ob + tid, F);
        float inv = LD(bng, obn + tid, F) * rsqrtf(LD(bnv, obn + tid, F) + BN_EPS);
        sA[tid] = inv;
        sB[tid] = LD(bnb, obn + tid, F) - LD(bnm, obn + tid, F) * inv;
    }
    int ln = tid >> 5, j = tid & 31;
    int n = blockIdx.x*8 + ln;
    float agg = csr_gather(hin, n, j);
    sh[ln][j] = hin[n*32 + j] + agg;
    __syncthreads();
    float t1 = sb1[j];
    #pragma unroll
    for (int i = 0; i < 32; i++) t1 += sh[ln][i] * sW1[i*32 + j];
    st[ln][j] = fmaxf(t1, 0.f);
    __syncthreads();
    float t2 = sb2[j];
    #pragma unroll
    for (int i = 0; i < 32; i++) t2 += st[ln][i] * sW2[i*32 + j];
    t2 = fmaxf(t2, 0.f);
    hout[n*32 + j] = t2 * sA[j] + sB[j];
}

// fused pool (range-based) + xd + xdbias; final h lives in g_hB
__global__ __launch_bounds__(256) void k_poolxd(const void* W, const void* bias,
                                                const void* c1b){
    const int F = g_isf32;
    __shared__ float red[8][32];
    __shared__ float sxd[128];
    int b = blockIdx.x, tid = threadIdx.x;
    int j = tid & 31, sub = tid >> 5;
    int s = g_gstart[b], e = g_gstart[b + 1];
    float a = 0.f;
    for (int n = s + sub; n < e; n += 8) a += g_hB[n*32 + j];
    red[sub][j] = a;
    __syncthreads();
    if (sub == 0){
        red[0][j] = red[0][j] + red[1][j] + red[2][j] + red[3][j]
                  + red[4][j] + red[5][j] + red[6][j] + red[7][j];
    }
    __syncthreads();
    if (tid < 128){
        float acc = LD(bias, tid, F);
        #pragma unroll
        for (int i = 0; i < 32; i++) acc += red[0][i] * LD(W, i*128 + tid, F);
        float xdv = fmaxf(acc, 0.f);
        g_xd[b*128 + tid] = xdv;
        sxd[tid] = xdv;
    }
    __syncthreads();
    if (tid < 32){
        float a2 = LD(c1b, tid, F);
        for (int c = 0; c < 128; c++) a2 += sxd[c] * g_wsum[tid*128 + c];
        g_xdb[b*32 + tid] = a2;
    }
}

// ---------------- conv1 prep (P table + wsum merged) ----------

__global__ void k_Pw(const void* embed, const void* c1W){
    const int F = g_isf32;
    if (blockIdx.x < 52){
        int idx = blockIdx.x*256 + threadIdx.x;
        if (idx >= 16*26*32) return;
        int o = idx & 31;
        int t = (idx >> 5) % 26;
        int k = idx / (32*26);
        float a = 0.f;
        for (int c = 0; c < 128; c++)
            a += LD(embed, t*128 + c, F) * LD(c1W, o*4096 + c*16 + k, F);
        g_P[(k*26 + t)*32 + o] = a;
    } else {
        int idx = (blockIdx.x - 52)*256 + threadIdx.x;   // 4096 threads
        int o = idx >> 7, c = idx & 127;
        float a = 0.f;
        #pragma unroll
        for (int k = 0; k < 16; k++) a += LD(c1W, o*4096 + (128 + c)*16 + k, F);
        g_wsum[o*128 + c] = a;
    }
}

// writes [b][o][w] (stride C1S); grid NB*4, each block does a w-quarter.
// P table read DIRECTLY from global (53 KB, L2-shared across all blocks;
// o = lane -> each gather is one coalesced 128B wave read). LDS holds only stg.
__global__ __launch_bounds__(256) void k_conv1L(
    const int* __restrict__ target,
    const void* g, const void* be, const void* m, const void* v, int obn)
{
    const int F = g_isf32;
    __shared__ int   stg[LSEQ];
    __shared__ float sxb[32], sA[32], sB[32];
    int b = blockIdx.x >> 2, q = blockIdx.x & 3;
    int tid = threadIdx.x;
    for (int i = tid; i < LSEQ; i += 256) stg[i] = target[b*LSEQ + i];
    if (tid < 32){
        sxb[tid] = g_xdb[b*32 + tid];
        float inv = LD(g, obn + tid, F) * rsqrtf(LD(v, obn + tid, F) + BN_EPS);
        sA[tid] = inv;
        sB[tid] = LD(be, obn + tid, F) - LD(m, obn + tid, F) * inv;
    }
    __syncthreads();
    int o = tid & 31, wsub = tid >> 5;
    float xb = sxb[o], aa = sA[o], bb = sB[o];
    int wlo = q*248;
    int whi = (q == 3) ? W1O : wlo + 248;
    for (int w = wlo + wsub; w < whi; w += 8){
        float a = xb;
        #pragma unroll
        for (int k = 0; k < 16; k++)
            a += g_P[(k*26 + stg[w + k])*32 + o];
        g_c1o[(b*32 + o)*C1S + w] = fmaxf(a * aa + bb, 0.f);
    }
}

// ---------------- conv2/conv3 via MFMA, double-bf16 split (FROZEN) ------

#define CT_W 128
#define CT_R 144     // 128 + 15 halo, padded
#define CPAD 40      // c-row pad: 80 B = 16B-aligned rows

__global__ __launch_bounds__(256) void k_cmfma(
    int sel, int Wvalid, int Wout, int inStride,
    const void* bias, const void* g, const void* be,
    const void* m, const void* v, int obn)
{
    const int F = g_isf32;
    const float* in = (sel == 0) ? g_c1o : g_c2o;
    __shared__ __attribute__((aligned(16))) unsigned short sAh[CT_R*CPAD]; // 11520 B
    __shared__ __attribute__((aligned(16))) unsigned short sAl[CT_R*CPAD]; // 11520 B
    __shared__ float sSc[32], sOf[32];
    int tid = threadIdx.x;
    int b = blockIdx.x >> 3;
    int tile = blockIdx.x & 7;
    int wbase = tile * CT_W;

    for (int c = 0; c < 32; c++){
        const float* src = in + (b*32 + c)*inStride;
        if (tid < CT_R){
            int wg_ = wbase + tid;
            float xv = (wg_ < Wvalid) ? src[wg_] : 0.f;
            unsigned short h = f2b(xv);
            sAh[tid*CPAD + c] = h;
            sAl[tid*CPAD + c] = f2b(xv - bb2f(h));
        }
    }
    if (tid < 32){
        float inv = LD(g, obn + tid, F) * rsqrtf(LD(v, obn + tid, F) + BN_EPS);
        sSc[tid] = inv;
        sOf[tid] = LD(be, obn + tid, F) + (LD(bias, tid, F) - LD(m, obn + tid, F)) * inv;
    }
    __syncthreads();                 // the ONLY barrier

    int lane = tid & 63;
    int wv = tid >> 6;
    int ml = lane & 15, quad = lane >> 4;
    int wgrp = wv & 1;
    int ogrp = wv >> 1;

    const s8v* wfb = (const s8v*)&g_wf[sel][0] + ogrp*128 + lane;

    f4v acc[4];
    #pragma unroll
    for (int mt = 0; mt < 4; mt++) acc[mt] = (f4v){0.f, 0.f, 0.f, 0.f};

    s8v nbh = wfb[0], nbl = wfb[64];
    for (int ktg = 0; ktg < 16; ktg++){
        s8v bh = nbh, bl = nbl;
        if (ktg < 15){
            nbh = wfb[(ktg + 1)*256];
            nbl = wfb[(ktg + 1)*256 + 64];
        }
        #pragma unroll
        for (int mt = 0; mt < 4; mt++){
            int row = wgrp*64 + mt*16 + ml + ktg;
            const int aidx = row*CPAD + quad*8;
            s8v ah = *(const s8v*)&sAh[aidx];
            s8v al = *(const s8v*)&sAl[aidx];
            acc[mt] = __builtin_amdgcn_mfma_f32_16x16x32_bf16(ah, bh, acc[mt], 0, 0, 0);
            acc[mt] = __builtin_amdgcn_mfma_f32_16x16x32_bf16(ah, bl, acc[mt], 0, 0, 0);
            acc[mt] = __builtin_amdgcn_mfma_f32_16x16x32_bf16(al, bh, acc[mt], 0, 0, 0);
        }
    }

    int o = ogrp*16 + ml;
    float sc = sSc[o], of = sOf[o];
    #pragma unroll
    for (int mt = 0; mt < 4; mt++){
        int w0 = wbase + wgrp*64 + mt*16 + quad*4;
        f4v a = acc[mt];
        float y0 = fmaxf(a.x*sc + of, 0.f);
        float y1 = fmaxf(a.y*sc + of, 0.f);
        float y2 = fmaxf(a.z*sc + of, 0.f);
        float y3 = fmaxf(a.w*sc + of, 0.f);
        if (sel == 0){
            float* dst = &g_c2o[(b*32 + o)*C2S + w0];
            if (w0 + 3 < Wout){
                *(float4*)dst = make_float4(y0, y1, y2, y3);
            } else if (w0 < Wout){
                dst[0] = y0;
                if (w0+1 < Wout) dst[1] = y1;
                if (w0+2 < Wout) dst[2] = y2;
                if (w0+3 < Wout) dst[3] = y3;
            }
        } else {
            if (w0 < Wout){
                float mx = y0;
                if (w0+1 < Wout) mx = fmaxf(mx, y1);
                if (w0+2 < Wout) mx = fmaxf(mx, y2);
                if (w0+3 < Wout) mx = fmaxf(mx, y3);
                atomicMax((int*)&g_xcm[b*32 + o], __float_as_int(mx));
            }
        }
    }
}

// ---------------- fused FC tail: xcf -> fc1 -> fc2 -> out (per-b) -----------

__global__ __launch_bounds__(1024) void k_tail(
    const void* fcxcW, const void* fcxcb,
    const void* bg, const void* bb, const void* bm, const void* bv,
    const void* fc1W, const void* fc1b,
    const void* fc2W, const void* fc2b,
    const void* outW, const void* outb, void* out)
{
    const int F = g_isf32;
    __shared__ float sz[256];
    __shared__ float z1s[1024];
    __shared__ float sp[4][256];
    int b = blockIdx.x, t = threadIdx.x;
    if (t < 128) sz[t] = g_xd[b*128 + t];
    else if (t < 256){
        int j = t - 128;
        float a = LD(fcxcb, j, F);
        #pragma unroll
        for (int i = 0; i < 32; i++) a += g_xcm[b*32 + i] * LD(fcxcW, i*128 + j, F);
        float inv = LD(bg, j, F) * rsqrtf(LD(bv, j, F) + BN_EPS);
        a = (a - LD(bm, j, F)) * inv + LD(bb, j, F);
        sz[t] = fmaxf(a, 0.f);
    }
    __syncthreads();
    float a = LD(fc1b, t, F);
    for (int i = 0; i < 256; i++) a += sz[i] * LD(fc1W, i*1024 + t, F);
    z1s[t] = fmaxf(a, 0.f);
    __syncthreads();
    int j = t & 255, kq = t >> 8;
    float a2 = 0.f;
    #pragma unroll 8
    for (int i = 0; i < 256; i++)
        a2 += z1s[kq*256 + i] * LD(fc2W, (kq*256 + i)*256 + j, F);
    sp[kq][j] = a2;
    __syncthreads();
    if (t < 256){
        float z2 = fmaxf(sp[0][t] + sp[1][t] + sp[2][t] + sp[3][t] + LD(fc2b, t, F), 0.f);
        sp[0][t] = z2 * LD(outW, t, F);
    }
    __syncthreads();
    for (int s = 128; s > 0; s >>= 1){
        if (t < s) sp[0][t] += sp[0][t + s];
        __syncthreads();
    }
    if (t == 0){
        float r = sp[0][0] + LD(outb, 0, F);
        if (F) ((float*)out)[b] = r;
        else   ((bf16*)out)[b] = __float2bfloat16(r);
    }
}

// ---------------- launch ----------------

extern "C" void kernel_launch(void* const* d_in, const int* in_sizes, int n_in,
                              void* d_out, int out_size, void* d_ws, size_t ws_size,
                              hipStream_t stream)
{
    (void)in_sizes; (void)n_in; (void)out_size; (void)d_ws; (void)ws_size;
    const void* x      = d_in[0];
    const int*  ei     = (const int*)d_in[1];
    const int*  batch  = (const int*)d_in[2];
    const int*  target = (const int*)d_in[3];
    const void* g1W1 = d_in[4];  const void* g1b1 = d_in[5];
    const void* g1W2 = d_in[6];  const void* g1b2 = d_in[7];
    const void* gW1  = d_in[8];  const void* gb1  = d_in[9];
    const void* gW2  = d_in[10]; const void* gb2  = d_in[11];
    const void* bng  = d_in[12]; const void* bnb  = d_in[13];
    const void* bnm  = d_in[14]; const void* bnv  = d_in[15];
    const void* fcxdW = d_in[16]; const void* fcxdb = d_in[17];
    const void* embed = d_in[18];
    const void* c1W = d_in[19]; const void* c1b = d_in[20];
    const void* c2W = d_in[21]; const void* c2b = d_in[22];
    const void* c3W = d_in[23]; const void* c3b = d_in[24];
    const void* cbng = d_in[25]; const void* cbnb = d_in[26];
    const void* cbnm = d_in[27]; const void* cbnv = d_in[28];
    const void* fcxcW = d_in[29]; const void* fcxcb = d_in[30];
    const void* bnfcg = d_in[31]; const void* bnfcb = d_in[32];
    const void* bnfcm = d_in[33]; const void* bnfcv = d_in[34];
    const void* fc1W = d_in[35]; const void* fc1b = d_in[36];
    const void* fc2W = d_in[37]; const void* fc2b = d_in[38];
    const void* outW = d_in[39]; const void* outb = d_in[40];

    k_dtype<<<1, 64, 0, stream>>>(x);
    k_wpack<<<256, 256, 0, stream>>>(c2W, c3W);
    k_Pw<<<68, 256, 0, stream>>>(embed, c1W);   // hoisted: only needs embed/c1W

    // ---- CSR build ----
    k_zero<<<(N_NODES + NB*32)/256, 256, 0, stream>>>();
    k_count<<<N_EDGES/256, 256, 0, stream>>>(ei);
    k_scan<<<1, 1024, 0, stream>>>();
    k_fill<<<N_EDGES/256, 256, 0, stream>>>(ei);
    k_ranges<<<1, 256, 0, stream>>>(batch);

    // ---- GIN chain (8 nodes/block; h ping-pongs hA->hB->hA->...) ----
    k_proj78<<<N_NODES/8, 256, 0, stream>>>(x, g1W1);
    k_gin1b<<<N_NODES/8, 256, 0, stream>>>(g1b1, g1W2, g1b2, bng, bnb, bnm, bnv);
    for (int l = 0; l < 4; l++){
        k_gin32L<<<N_NODES/8, 256, 0, stream>>>(gW1, gb1, gW2, gb2,
                                                bng, bnb, bnm, bnv, l);
    }
    // ---- pool+xd+xdbias fused ----
    k_poolxd<<<NB, 256, 0, stream>>>(fcxdW, fcxdb, c1b);
    // ---- conv chain ----
    k_conv1L<<<NB*4, 256, 0, stream>>>(target, cbng, cbnb, cbnm, cbnv, 0);
    k_cmfma<<<NB*8, 256, 0, stream>>>(0, W1O, W2O, C1S,
                                      c2b, cbng, cbnb, cbnm, cbnv, 32);
    k_cmfma<<<NB*8, 256, 0, stream>>>(1, W2O, W3O, C2S,
                                      c3b, cbng, cbnb, cbnm, cbnv, 64);
    // ---- fused FC tail ----
    k_tail<<<NB, 1024, 0, stream>>>(fcxcW, fcxcb, bnfcg, bnfcb, bnfcm, bnfcv,
                                    fc1W, fc1b, fc2W, fc2b, outW, outb, d_out);
}

// Round 18
// 439.357 us; speedup vs baseline: 1.0957x; 1.0869x over previous
//
#include <hip/hip_runtime.h>
#include <hip/hip_bf16.h>

typedef __hip_bfloat16 bf16;
__device__ __forceinline__ float b2f(bf16 v){ return __bfloat162float(v); }

typedef __attribute__((ext_vector_type(8))) short s8v;
typedef __attribute__((ext_vector_type(4))) float f4v;

#define N_NODES 16384
#define N_EDGES 65536
#define NB 256
#define LSEQ 1000
#define BN_EPS 1e-5f
#define W1O 985
#define W2O 970
#define W3O 955

// ---- dtype flag: 1 if float inputs are f32, 0 if bf16 (measured: f32 on this harness) ----
__device__ int g_isf32;

__device__ __forceinline__ float LD(const void* p, int i, int f){
    return f ? ((const float*)p)[i] : b2f(((const bf16*)p)[i]);
}

// f32 -> bf16 bits, round-to-nearest-even
__device__ __forceinline__ unsigned short f2b(float x){
    unsigned u = __float_as_uint(x);
    return (unsigned short)((u + 0x7FFFu + ((u >> 16) & 1u)) >> 16);
}
__device__ __forceinline__ float bb2f(unsigned short h){
    return __uint_as_float(((unsigned)h) << 16);
}

__global__ void k_dtype(const void* x){
    if (threadIdx.x != 0 || blockIdx.x != 0) return;
    const unsigned short* u = (const unsigned short*)x;
    int insane = 0;
    for (int i = 0; i < 512; i++){
        unsigned short h = u[i];
        int ex = (h >> 7) & 0xFF;
        if (!(h == 0 || (ex >= 96 && ex <= 142))) insane++;
    }
    g_isf32 = (insane > 50) ? 1 : 0;
}

// ---- intermediates in device globals ----
__device__ float g_hA[N_NODES*32];
__device__ float g_hB[N_NODES*32];
__device__ float g_xd[NB*128];
__device__ float g_P[16*26*32];
__device__ float g_wsum[32*128];
__device__ float g_xdb[NB*32];
__device__ float g_xcm[NB*32];
// pre-packed conv weights in per-lane B-FRAGMENT order (s8v granularity):
// s8v index = ktg*256 + ogrp*128 + hl*64 + lane
__device__ __attribute__((aligned(16))) unsigned short g_wf[2][32768];
// CSR of the (fixed) edge list, destination-major
__device__ int g_deg[N_NODES];
__device__ int g_cur[N_NODES];
__device__ int g_rowptr[N_NODES + 1];
__device__ int g_csrc[N_EDGES];
__device__ int g_gstart[NB + 1];     // per-graph node ranges (batch is sorted)

// merged zeroing: deg (16384 ints) + xcm (8192 floats); grid 96
__global__ void k_zero(){
    int i = blockIdx.x*256 + threadIdx.x;
    if (i < N_NODES) g_deg[i] = 0;
    else g_xcm[i - N_NODES] = 0.f;
}

// ---- CSR build (once per launch) ----
__global__ void k_count(const int* __restrict__ ei){
    int e = blockIdx.x*256 + threadIdx.x;                                    // grid 256
    atomicAdd(&g_deg[ei[N_EDGES + e]], 1);
}
__global__ __launch_bounds__(1024) void k_scan(){                            // 1 block
    __shared__ int part[1024];
    int t = threadIdx.x;
    int base = t*16;
    int s = 0;
    #pragma unroll
    for (int i = 0; i < 16; i++) s += g_deg[base + i];
    part[t] = s;
    __syncthreads();
    for (int off = 1; off < 1024; off <<= 1){
        int v = (t >= off) ? part[t - off] : 0;
        __syncthreads();
        part[t] += v;
        __syncthreads();
    }
    int run = (t == 0) ? 0 : part[t - 1];
    for (int i = 0; i < 16; i++){
        g_rowptr[base + i] = run;
        g_cur[base + i] = run;
        run += g_deg[base + i];
    }
    if (t == 1023) g_rowptr[N_NODES] = run;
}
__global__ void k_fill(const int* __restrict__ ei){
    int e = blockIdx.x*256 + threadIdx.x;                                    // grid 256
    int d = ei[N_EDGES + e];
    int slot = atomicAdd(&g_cur[d], 1);
    g_csrc[slot] = ei[e];
}
__global__ void k_ranges(const int* __restrict__ batch){                     // 1 block, 256 thr
    int b = threadIdx.x;
    int lo = 0, hi = N_NODES;
    while (lo < hi){ int mid = (lo + hi) >> 1; if (batch[mid] < b) lo = mid + 1; else hi = mid; }
    g_gstart[b] = lo;
    if (b == 0) g_gstart[NB] = N_NODES;
}

// ---- weight pre-pack into fragment order ----
__global__ void k_wpack(const void* w2, const void* w3){
    const int F = g_isf32;
    int idx = blockIdx.x*256 + threadIdx.x;      // 65536 threads
    int sel = idx >> 15;
    int r = idx & 32767;
    int j = r & 7;
    int lane = (r >> 3) & 63;
    int hl = (r >> 9) & 1;
    int ogrp = (r >> 10) & 1;
    int ktg = r >> 11;
    int c = (lane >> 4)*8 + j;
    int o = ogrp*16 + (lane & 15);
    const void* Wt = sel ? w3 : w2;
    float wv = LD(Wt, o*512 + c*16 + ktg, F);
    unsigned short h = f2b(wv);
    g_wf[sel][r] = hl ? f2b(wv - bb2f(h)) : h;
}

// ---------------- GIN branch (CSR gather fused; 8 nodes per block) ----------

__global__ __launch_bounds__(256) void k_proj78(const void* x, const void* W1)
{
    const int F = g_isf32;
    __shared__ float sW1[78*32];
    __shared__ float sx[8][78];
    int tid = threadIdx.x;
    for (int i = tid; i < 78*32; i += 256) sW1[i] = LD(W1, i, F);
    int nodeBase = blockIdx.x * 8;
    for (int i = tid; i < 8*78; i += 256){
        int ln = i / 78, f = i - ln*78;
        sx[ln][f] = LD(x, (nodeBase + ln)*78 + f, F);
    }
    __syncthreads();
    int ln = tid >> 5, j = tid & 31;
    float a = 0.f;
    #pragma unroll 6
    for (int i = 0; i < 78; i++) a += sx[ln][i] * sW1[i*32 + j];
    g_hA[(nodeBase + ln)*32 + j] = a;
}

// cooperative edge gather: 32 lanes of a node load up to 32 indices at once,
// broadcast via shuffle -> feature gathers become independent (same sum order)
__device__ __forceinline__ float csr_gather(const float* hin, int n, int j){
    int rs = g_rowptr[n];
    int deg = g_rowptr[n + 1] - rs;
    float agg = 0.f;
    for (int base = 0; base < deg; base += 32){
        int cnt = deg - base; if (cnt > 32) cnt = 32;
        int myidx = (j < cnt) ? g_csrc[rs + base + j] : 0;
        for (int e = 0; e < cnt; e++){
            int src = __shfl(myidx, e, 32);
            agg += hin[src*32 + j];
        }
    }
    return agg;
}

// hA -> hB
__global__ __launch_bounds__(256) void k_gin1b(
    const void* b1, const void* W2, const void* b2,
    const void* bng, const void* bnb, const void* bnm, const void* bnv)
{
    const int F = g_isf32;
    __shared__ float sW2[32*32];
    __shared__ float sb1[32], sb2[32], sA[32], sB[32];
    __shared__ float st[8][32];
    int tid = threadIdx.x;
    for (int i = tid; i < 1024; i += 256) sW2[i] = LD(W2, i, F);
    if (tid < 32){
        sb1[tid] = LD(b1, tid, F); sb2[tid] = LD(b2, tid, F);
        float inv = LD(bng, tid, F) * rsqrtf(LD(bnv, tid, F) + BN_EPS);
        sA[tid] = inv;
        sB[tid] = LD(bnb, tid, F) - LD(bnm, tid, F) * inv;
    }
    __syncthreads();
    int ln = tid >> 5, j = tid & 31;
    int n = blockIdx.x*8 + ln;
    float agg = csr_gather(g_hA, n, j);
    st[ln][j] = fmaxf(g_hA[n*32 + j] + agg + sb1[j], 0.f);
    __syncthreads();
    float t2 = sb2[j];
    #pragma unroll
    for (int i = 0; i < 32; i++) t2 += st[ln][i] * sW2[i*32 + j];
    t2 = fmaxf(t2, 0.f);
    g_hB[n*32 + j] = t2 * sA[j] + sB[j];
}

// alternating hB->hA (l even) / hA->hB (l odd)
__global__ __launch_bounds__(256) void k_gin32L(
    const void* W1, const void* b1, const void* W2, const void* b2,
    const void* bng, const void* bnb, const void* bnm, const void* bnv, int l)
{
    const int F = g_isf32;
    const float* hin = (l & 1) ? g_hA : g_hB;
    float* hout = (l & 1) ? g_hB : g_hA;
    const int oW = l*1024, ob = l*32, obn = (l+1)*32;
    __shared__ float sW1[32*32], sW2[32*32];
    __shared__ float sb1[32], sb2[32], sA[32], sB[32];
    __shared__ float sh[8][32], st[8][32];
    int tid = threadIdx.x;
    for (int i = tid; i < 1024; i += 256){ sW1[i] = LD(W1, oW + i, F); sW2[i] = LD(W2, oW + i, F); }
    if (tid < 32){
        sb1[tid] = LD(b1, ob + tid, F); sb2[tid] = LD(b2, ob + tid, F);
        float inv = LD(bng, obn + tid, F) * rsqrtf(LD(bnv, obn + tid, F) + BN_EPS);
        sA[tid] = inv;
        sB[tid] = LD(bnb, obn + tid, F) - LD(bnm, obn + tid, F) * inv;
    }
    int ln = tid >> 5, j = tid & 31;
    int n = blockIdx.x*8 + ln;
    float agg = csr_gather(hin, n, j);
    sh[ln][j] = hin[n*32 + j] + agg;
    __syncthreads();
    float t1 = sb1[j];
    #pragma unroll
    for (int i = 0; i < 32; i++) t1 += sh[ln][i] * sW1[i*32 + j];
    st[ln][j] = fmaxf(t1, 0.f);
    __syncthreads();
    float t2 = sb2[j];
    #pragma unroll
    for (int i = 0; i < 32; i++) t2 += st[ln][i] * sW2[i*32 + j];
    t2 = fmaxf(t2, 0.f);
    hout[n*32 + j] = t2 * sA[j] + sB[j];
}

// fused pool (range-based) + xd + xdbias; final h lives in g_hB
__global__ __launch_bounds__(256) void k_poolxd(const void* W, const void* bias,
                                                const void* c1b){
    const int F = g_isf32;
    __shared__ float red[8][32];
    __shared__ float sxd[128];
    int b = blockIdx.x, tid = threadIdx.x;
    int j = tid & 31, sub = tid >> 5;
    int s = g_gstart[b], e = g_gstart[b + 1];
    float a = 0.f;
    for (int n = s + sub; n < e; n += 8) a += g_hB[n*32 + j];
    red[sub][j] = a;
    __syncthreads();
    if (sub == 0){
        red[0][j] = red[0][j] + red[1][j] + red[2][j] + red[3][j]
                  + red[4][j] + red[5][j] + red[6][j] + red[7][j];
    }
    __syncthreads();
    if (tid < 128){
        float acc = LD(bias, tid, F);
        #pragma unroll
        for (int i = 0; i < 32; i++) acc += red[0][i] * LD(W, i*128 + tid, F);
        float xdv = fmaxf(acc, 0.f);
        g_xd[b*128 + tid] = xdv;
        sxd[tid] = xdv;
    }
    __syncthreads();
    if (tid < 32){
        float a2 = LD(c1b, tid, F);
        for (int c = 0; c < 128; c++) a2 += sxd[c] * g_wsum[tid*128 + c];
        g_xdb[b*32 + tid] = a2;
    }
}

// ---------------- conv1 prep (P table + wsum merged) ----------

__global__ void k_Pw(const void* embed, const void* c1W){
    const int F = g_isf32;
    if (blockIdx.x < 52){
        int idx = blockIdx.x*256 + threadIdx.x;
        if (idx >= 16*26*32) return;
        int o = idx & 31;
        int t = (idx >> 5) % 26;
        int k = idx / (32*26);
        float a = 0.f;
        for (int c = 0; c < 128; c++)
            a += LD(embed, t*128 + c, F) * LD(c1W, o*4096 + c*16 + k, F);
        g_P[(k*26 + t)*32 + o] = a;
    } else {
        int idx = (blockIdx.x - 52)*256 + threadIdx.x;   // 4096 threads
        int o = idx >> 7, c = idx & 127;
        float a = 0.f;
        #pragma unroll
        for (int k = 0; k < 16; k++) a += LD(c1W, o*4096 + (128 + c)*16 + k, F);
        g_wsum[o*128 + c] = a;
    }
}

// ---------------- FUSED conv1+conv2+conv3 -------------------------------
// One block = one 128-w conv3 output tile for one b. Phases:
//  A: conv1 rows [0,160) (halo; math identical to old k_conv1L) -> LDS hi/lo
//  B: conv2 rows [0,144) via MFMA (ktg-ascending, per-output order identical
//     to the old k_cmfma -> bit-identical values)              -> LDS hi/lo
//  C: conv3 rows [0,128) (old frozen structure verbatim)       -> atomicMax
// Kills g_c1o/g_c2o round-trips and 2 dispatch boundaries; halo recompute
// in phase A is ~19% of conv1 work.

#define FT_W 128
#define C1R 160      // need rows 0..158
#define C2R 144      // need rows 0..142 read, 0..143 written
#define CPAD 40      // 80 B rows: 16B-aligned, 2-way bank alias (free)
#define STGN 176

__global__ __launch_bounds__(256) void k_cfuse(
    const int* __restrict__ target,
    const void* g, const void* be, const void* m, const void* v,   // cbn* stacked [3][32]
    const void* c2b, const void* c3b)
{
    const int F = g_isf32;
    __shared__ int stg[STGN];
    __shared__ __attribute__((aligned(16))) unsigned short sC1h[C1R*CPAD]; // 12800 B
    __shared__ __attribute__((aligned(16))) unsigned short sC1l[C1R*CPAD]; // 12800 B
    __shared__ __attribute__((aligned(16))) unsigned short sC2h[C2R*CPAD]; // 11520 B
    __shared__ __attribute__((aligned(16))) unsigned short sC2l[C2R*CPAD]; // 11520 B
    __shared__ float sxb[32], sA1[32], sB1[32], sSc2[32], sOf2[32], sSc3[32], sOf3[32];
    int b = blockIdx.x >> 3;
    int tile = blockIdx.x & 7;
    int wbase = tile * FT_W;
    int tid = threadIdx.x;

    for (int i = tid; i < STGN; i += 256){
        int gi = wbase + i;
        stg[i] = (gi < LSEQ) ? target[b*LSEQ + gi] : 0;
    }
    if (tid < 32){
        sxb[tid] = g_xdb[b*32 + tid];
        float i1 = LD(g, tid, F) * rsqrtf(LD(v, tid, F) + BN_EPS);
        sA1[tid] = i1;
        sB1[tid] = LD(be, tid, F) - LD(m, tid, F) * i1;
        float i2 = LD(g, 32 + tid, F) * rsqrtf(LD(v, 32 + tid, F) + BN_EPS);
        sSc2[tid] = i2;
        sOf2[tid] = LD(be, 32 + tid, F) + (LD(c2b, tid, F) - LD(m, 32 + tid, F)) * i2;
        float i3 = LD(g, 64 + tid, F) * rsqrtf(LD(v, 64 + tid, F) + BN_EPS);
        sSc3[tid] = i3;
        sOf3[tid] = LD(be, 64 + tid, F) + (LD(c3b, tid, F) - LD(m, 64 + tid, F)) * i3;
    }
    __syncthreads();

    // ---- Phase A: conv1 (table gather, math identical to old k_conv1L) ----
    {
        int o = tid & 31, rsub = tid >> 5;
        for (int r = rsub; r < C1R; r += 8){
            float val = 0.f;
            if (wbase + r < W1O){
                float a = sxb[o];
                #pragma unroll
                for (int k = 0; k < 16; k++)
                    a += g_P[(k*26 + stg[r + k])*32 + o];
                val = fmaxf(a * sA1[o] + sB1[o], 0.f);
            }
            unsigned short h = f2b(val);
            sC1h[r*CPAD + o] = h;
            sC1l[r*CPAD + o] = f2b(val - bb2f(h));
        }
    }
    __syncthreads();

    int lane = tid & 63;
    int wv = tid >> 6;
    int ml = lane & 15, quad = lane >> 4;
    int wgrp = wv & 1;
    int ogrp = wv >> 1;
    int oo = ogrp*16 + ml;

    // ---- Phase B: conv2 rows [0,144); m-tiles mt = wgrp + 2i ----
    {
        const s8v* wfb = (const s8v*)&g_wf[0][0] + ogrp*128 + lane;
        int nmt = 5 - wgrp;                  // wgrp0: mt 0,2,4,6,8 ; wgrp1: 1,3,5,7
        f4v acc[5];
        #pragma unroll
        for (int i = 0; i < 5; i++) acc[i] = (f4v){0.f,0.f,0.f,0.f};
        s8v nbh = wfb[0], nbl = wfb[64];
        for (int ktg = 0; ktg < 16; ktg++){
            s8v bh = nbh, bl = nbl;
            if (ktg < 15){ nbh = wfb[(ktg+1)*256]; nbl = wfb[(ktg+1)*256 + 64]; }
            #pragma unroll
            for (int i = 0; i < 5; i++){
                if (i < nmt){
                    int row = (wgrp + 2*i)*16 + ml + ktg;       // <= 158
                    int aidx = row*CPAD + quad*8;
                    s8v ah = *(const s8v*)&sC1h[aidx];
                    s8v al = *(const s8v*)&sC1l[aidx];
                    acc[i] = __builtin_amdgcn_mfma_f32_16x16x32_bf16(ah, bh, acc[i], 0, 0, 0);
                    acc[i] = __builtin_amdgcn_mfma_f32_16x16x32_bf16(ah, bl, acc[i], 0, 0, 0);
                    acc[i] = __builtin_amdgcn_mfma_f32_16x16x32_bf16(al, bh, acc[i], 0, 0, 0);
                }
            }
        }
        float sc = sSc2[oo], of = sOf2[oo];
        #pragma unroll
        for (int i = 0; i < 5; i++){
            if (i < nmt){
                int mt = wgrp + 2*i;
                f4v a = acc[i];
                float ys[4] = {a.x, a.y, a.z, a.w};
                #pragma unroll
                for (int rr = 0; rr < 4; rr++){
                    int row = mt*16 + quad*4 + rr;              // <= 143
                    float y = fmaxf(ys[rr]*sc + of, 0.f);
                    unsigned short h = f2b(y);
                    sC2h[row*CPAD + oo] = h;
                    sC2l[row*CPAD + oo] = f2b(y - bb2f(h));
                }
            }
        }
    }
    __syncthreads();

    // ---- Phase C: conv3 (frozen structure) + maxpool epilogue ----
    {
        const s8v* wfb = (const s8v*)&g_wf[1][0] + ogrp*128 + lane;
        f4v acc[4];
        #pragma unroll
        for (int mt = 0; mt < 4; mt++) acc[mt] = (f4v){0.f,0.f,0.f,0.f};
        s8v nbh = wfb[0], nbl = wfb[64];
        for (int ktg = 0; ktg < 16; ktg++){
            s8v bh = nbh, bl = nbl;
            if (ktg < 15){ nbh = wfb[(ktg+1)*256]; nbl = wfb[(ktg+1)*256 + 64]; }
            #pragma unroll
            for (int mt = 0; mt < 4; mt++){
                int row = wgrp*64 + mt*16 + ml + ktg;           // <= 142
                int aidx = row*CPAD + quad*8;
                s8v ah = *(const s8v*)&sC2h[aidx];
                s8v al = *(const s8v*)&sC2l[aidx];
                acc[mt] = __builtin_amdgcn_mfma_f32_16x16x32_bf16(ah, bh, acc[mt], 0, 0, 0);
                acc[mt] = __builtin_amdgcn_mfma_f32_16x16x32_bf16(ah, bl, acc[mt], 0, 0, 0);
                acc[mt] = __builtin_amdgcn_mfma_f32_16x16x32_bf16(al, bh, acc[mt], 0, 0, 0);
            }
        }
        float sc = sSc3[oo], of = sOf3[oo];
        #pragma unroll
        for (int mt = 0; mt < 4; mt++){
            int w0 = wbase + wgrp*64 + mt*16 + quad*4;
            f4v a = acc[mt];
            float y0 = fmaxf(a.x*sc + of, 0.f);
            float y1 = fmaxf(a.y*sc + of, 0.f);
            float y2 = fmaxf(a.z*sc + of, 0.f);
            float y3 = fmaxf(a.w*sc + of, 0.f);
            if (w0 < W3O){
                float mx = y0;
                if (w0+1 < W3O) mx = fmaxf(mx, y1);
                if (w0+2 < W3O) mx = fmaxf(mx, y2);
                if (w0+3 < W3O) mx = fmaxf(mx, y3);
                atomicMax((int*)&g_xcm[b*32 + oo], __float_as_int(mx));
            }
        }
    }
}

// ---------------- fused FC tail: xcf -> fc1 -> fc2 -> out (per-b) -----------

__global__ __launch_bounds__(1024) void k_tail(
    const void* fcxcW, const void* fcxcb,
    const void* bg, const void* bb, const void* bm, const void* bv,
    const void* fc1W, const void* fc1b,
    const void* fc2W, const void* fc2b,
    const void* outW, const void* outb, void* out)
{
    const int F = g_isf32;
    __shared__ float sz[256];
    __shared__ float z1s[1024];
    __shared__ float sp[4][256];
    int b = blockIdx.x, t = threadIdx.x;
    if (t < 128) sz[t] = g_xd[b*128 + t];
    else if (t < 256){
        int j = t - 128;
        float a = LD(fcxcb, j, F);
        #pragma unroll
        for (int i = 0; i < 32; i++) a += g_xcm[b*32 + i] * LD(fcxcW, i*128 + j, F);
        float inv = LD(bg, j, F) * rsqrtf(LD(bv, j, F) + BN_EPS);
        a = (a - LD(bm, j, F)) * inv + LD(bb, j, F);
        sz[t] = fmaxf(a, 0.f);
    }
    __syncthreads();
    float a = LD(fc1b, t, F);
    for (int i = 0; i < 256; i++) a += sz[i] * LD(fc1W, i*1024 + t, F);
    z1s[t] = fmaxf(a, 0.f);
    __syncthreads();
    int j = t & 255, kq = t >> 8;
    float a2 = 0.f;
    #pragma unroll 8
    for (int i = 0; i < 256; i++)
        a2 += z1s[kq*256 + i] * LD(fc2W, (kq*256 + i)*256 + j, F);
    sp[kq][j] = a2;
    __syncthreads();
    if (t < 256){
        float z2 = fmaxf(sp[0][t] + sp[1][t] + sp[2][t] + sp[3][t] + LD(fc2b, t, F), 0.f);
        sp[0][t] = z2 * LD(outW, t, F);
    }
    __syncthreads();
    for (int s = 128; s > 0; s >>= 1){
        if (t < s) sp[0][t] += sp[0][t + s];
        __syncthreads();
    }
    if (t == 0){
        float r = sp[0][0] + LD(outb, 0, F);
        if (F) ((float*)out)[b] = r;
        else   ((bf16*)out)[b] = __float2bfloat16(r);
    }
}

// ---------------- launch ----------------

extern "C" void kernel_launch(void* const* d_in, const int* in_sizes, int n_in,
                              void* d_out, int out_size, void* d_ws, size_t ws_size,
                              hipStream_t stream)
{
    (void)in_sizes; (void)n_in; (void)out_size; (void)d_ws; (void)ws_size;
    const void* x      = d_in[0];
    const int*  ei     = (const int*)d_in[1];
    const int*  batch  = (const int*)d_in[2];
    const int*  target = (const int*)d_in[3];
    const void* g1W1 = d_in[4];  const void* g1b1 = d_in[5];
    const void* g1W2 = d_in[6];  const void* g1b2 = d_in[7];
    const void* gW1  = d_in[8];  const void* gb1  = d_in[9];
    const void* gW2  = d_in[10]; const void* gb2  = d_in[11];
    const void* bng  = d_in[12]; const void* bnb  = d_in[13];
    const void* bnm  = d_in[14]; const void* bnv  = d_in[15];
    const void* fcxdW = d_in[16]; const void* fcxdb = d_in[17];
    const void* embed = d_in[18];
    const void* c1W = d_in[19]; const void* c1b = d_in[20];
    const void* c2W = d_in[21]; const void* c2b = d_in[22];
    const void* c3W = d_in[23]; const void* c3b = d_in[24];
    const void* cbng = d_in[25]; const void* cbnb = d_in[26];
    const void* cbnm = d_in[27]; const void* cbnv = d_in[28];
    const void* fcxcW = d_in[29]; const void* fcxcb = d_in[30];
    const void* bnfcg = d_in[31]; const void* bnfcb = d_in[32];
    const void* bnfcm = d_in[33]; const void* bnfcv = d_in[34];
    const void* fc1W = d_in[35]; const void* fc1b = d_in[36];
    const void* fc2W = d_in[37]; const void* fc2b = d_in[38];
    const void* outW = d_in[39]; const void* outb = d_in[40];

    k_dtype<<<1, 64, 0, stream>>>(x);
    k_wpack<<<256, 256, 0, stream>>>(c2W, c3W);
    k_Pw<<<68, 256, 0, stream>>>(embed, c1W);

    // ---- CSR build ----
    k_zero<<<(N_NODES + NB*32)/256, 256, 0, stream>>>();
    k_count<<<N_EDGES/256, 256, 0, stream>>>(ei);
    k_scan<<<1, 1024, 0, stream>>>();
    k_fill<<<N_EDGES/256, 256, 0, stream>>>(ei);
    k_ranges<<<1, 256, 0, stream>>>(batch);

    // ---- GIN chain (8 nodes/block; h ping-pongs hA->hB->hA->...) ----
    k_proj78<<<N_NODES/8, 256, 0, stream>>>(x, g1W1);
    k_gin1b<<<N_NODES/8, 256, 0, stream>>>(g1b1, g1W2, g1b2, bng, bnb, bnm, bnv);
    for (int l = 0; l < 4; l++){
        k_gin32L<<<N_NODES/8, 256, 0, stream>>>(gW1, gb1, gW2, gb2,
                                                bng, bnb, bnm, bnv, l);
    }
    // ---- pool+xd+xdbias fused ----
    k_poolxd<<<NB, 256, 0, stream>>>(fcxdW, fcxdb, c1b);
    // ---- FUSED conv chain (one dispatch) ----
    k_cfuse<<<NB*8, 256, 0, stream>>>(target, cbng, cbnb, cbnm, cbnv, c2b, c3b);
    // ---- fused FC tail ----
    k_tail<<<NB, 1024, 0, stream>>>(fcxcW, fcxcb, bnfcg, bnfcb, bnfcm, bnfcv,
                                    fc1W, fc1b, fc2W, fc2b, outW, outb, d_out);
}